// Round 11
// baseline (121.518 us; speedup 1.0000x reference)
//
#include <hip/hip_runtime.h>

typedef __fp16 f16x4 __attribute__((ext_vector_type(4)));
typedef __fp16 f16x2 __attribute__((ext_vector_type(2)));
typedef float f32x4 __attribute__((ext_vector_type(4)));

__device__ __forceinline__ f16x4 cat(f16x2 lo, f16x2 hi) {
    return __builtin_shufflevector(lo, hi, 0, 1, 2, 3);
}
__device__ __forceinline__ f16x2 u2h(unsigned v) {
    union { unsigned u; f16x2 h; } x; x.u = v; return x.h;
}
template <int CTRL>
__device__ __forceinline__ float dpp_add(float v) {
    int s = __builtin_amdgcn_update_dpp(0, __float_as_int(v), CTRL, 0xf, 0xf, true);
    return v + __int_as_float(s);
}

// DIAGNOSTIC (R11): R9's persistent depth-1-prefetch structure with THREE
// redundant compute reps per sample (opaque-zero input perturbation defeats
// CSE; result = (r0+r1+r2)/3, ~1ulp noise). Purpose: (1) push kernel past
// the 41us poison-fill dispatches into rocprof top-5 -> first full counters
// since R1; (2) the duration itself discriminates the cold-cost theory:
//   ~38-42us => latency-bound and 3x cover now hides it (fix: batch loads)
//   ~51-55us => register prefetch is being drained by a conservative
//               vmcnt at the consume point (fix: producer/consumer waves)
//   FETCH_SIZE >> 64MB => bandwidth pathology; VGPR/Occupancy => regalloc.
// Per-sample algorithm unchanged (R7): single float4 load; xB derived via
// D = x_A * I_B; chain A_{s+1}=x*A_s repacked via pkrtz; trace reduction
// via 2-MFMA passes; lane-parallel polynomial epilogue.
__global__ __launch_bounds__(256, 6) void acoef_kernel(
    const float* __restrict__ x,
    const float* __restrict__ coef,
    float* __restrict__ out,
    int B)
{
    const int lane = threadIdx.x & 63;
    const int wid  = (blockIdx.x * 256 + (int)threadIdx.x) >> 6;
    const int nw   = gridDim.x * 4;

    const int n = lane & 15;
    const int q = lane >> 4;
    const bool diagsel = ((n >> 2) == q);

    unsigned ilo = 0, ihi = 0;
    if (diagsel) {
        ilo = ((n & 3) == 0 ? 0x3C00u : 0u) | ((n & 3) == 1 ? 0x3C000000u : 0u);
        ihi = ((n & 3) == 2 ? 0x3C00u : 0u) | ((n & 3) == 3 ? 0x3C000000u : 0u);
    }
    const f16x4 idB = cat(u2h(ilo), u2h(ihi));
    unsigned slo = (n == 0 ? 0x3C00u : 0u) | (n == 1 ? 0x3C000000u : 0u);
    unsigned shi = (n == 2 ? 0x3C00u : 0u) | (n == 3 ? 0x3C000000u : 0u);
    const f16x4 selB  = cat(u2h(slo), u2h(shi));
    const f16x4 onesA = cat(u2h(0x3C003C00u), u2h(0x3C003C00u));
    const f32x4 zero  = {0.f, 0.f, 0.f, 0.f};

    float4 cf[3]; float scl[3];
    #pragma unroll
    for (int p = 0; p < 3; ++p) {
        int s = 4 * p + n;
        int idx = s > 9 ? 9 : s;
        cf[p]  = *(const float4*)(coef + 4 * idx);
        scl[p] = __int_as_float((127 - 8 * s) << 23);
    }

    const int laneoff = n * 16 + 4 * q;

    int s = wid;
    float4 cur = *(const float4*)(x + (size_t)s * 256 + laneoff);

    #pragma unroll 1
    while (true) {
        const int s2 = s + nw;
        const bool more = (s2 < B);
        float4 nxt = *(const float4*)(x + (size_t)(more ? s2 : s) * 256 + laneoff);

        float resacc = 0.0f;
        #pragma unroll 1
        for (int rep = 0; rep < 3; ++rep) {
            float z = 0.0f;
            asm volatile("" : "+v"(z));   // opaque 0: forces full recompute per rep

            f16x4 xA = cat(__builtin_amdgcn_cvt_pkrtz(cur.x + z, cur.y),
                           __builtin_amdgcn_cvt_pkrtz(cur.z, cur.w));
            f32x4 d = __builtin_amdgcn_mfma_f32_16x16x16f16(xA, idB, zero, 0, 0, 0);
            f16x4 xB = cat(__builtin_amdgcn_cvt_pkrtz(d[0], d[1]),
                           __builtin_amdgcn_cvt_pkrtz(d[2], d[3]));

            f32x4 acc = __builtin_amdgcn_mfma_f32_16x16x16f16(xA, xB, zero, 0, 0, 0);

            f16x2 prpk[6];
            float trf = 0.0f;
            #pragma unroll
            for (int st = 0; st < 10; ++st) {
                float sA = (n & 1) ? acc[1] : acc[0];
                float sB = (n & 1) ? acc[3] : acc[2];
                float dv = (n & 2) ? sB : sA;
                float tr = diagsel ? dv : 0.0f;
                if (st & 1) prpk[st >> 1] = __builtin_amdgcn_cvt_pkrtz(trf, tr);
                else        trf = tr;

                if (st < 9) {
                    f16x4 bf = cat(__builtin_amdgcn_cvt_pkrtz(acc[0], acc[1]),
                                   __builtin_amdgcn_cvt_pkrtz(acc[2], acc[3]));
                    acc = __builtin_amdgcn_mfma_f32_16x16x16f16(xA, bf, zero, 0, 0, 0);
                }
            }
            prpk[5] = u2h(0u);

            float result = 0.0f;
            #pragma unroll
            for (int p = 0; p < 3; ++p) {
                f16x4 Ap = cat(prpk[2 * p], prpk[2 * p + 1]);
                f32x4 c1 = __builtin_amdgcn_mfma_f32_16x16x16f16(Ap, selB, zero, 0, 0, 0);
                f16x4 Bp = cat(__builtin_amdgcn_cvt_pkrtz(c1[0], c1[1]),
                               __builtin_amdgcn_cvt_pkrtz(c1[2], c1[3]));
                f32x4 c2 = __builtin_amdgcn_mfma_f32_16x16x16f16(onesA, Bp, zero, 0, 0, 0);
                float t = c2[0];
                float sv = t * 0x1p-8f;
                float h = fmaf(sv, cf[p].w, cf[p].z);
                h = fmaf(sv, h, cf[p].y);
                h = fmaf(sv, h, cf[p].x);
                result = fmaf(sv * h, scl[p], result);
            }
            result = dpp_add<0xB1>(result);
            result = dpp_add<0x4E>(result);
            resacc += result;
        }

        if (lane == 0) out[s] = resacc * (1.0f / 3.0f);

        if (!more) break;
        s = s2; cur = nxt;
    }
}

extern "C" void kernel_launch(void* const* d_in, const int* in_sizes, int n_in,
                              void* d_out, int out_size, void* d_ws, size_t ws_size,
                              hipStream_t stream) {
    const float* x    = (const float*)d_in[0];   // [65536, 16, 16] fp32
    const float* coef = (const float*)d_in[1];   // [10, 4] fp32
    float* out        = (float*)d_out;           // [65536] fp32
    const int B = in_sizes[0] / 256;             // 65536 samples
    // 1536 blocks = exactly 6 blocks/CU resident, 6144 persistent waves
    acoef_kernel<<<dim3(1536), dim3(256), 0, stream>>>(x, coef, out, B);
}

// Round 12
// 102.593 us; speedup vs baseline: 1.1845x; 1.1845x over previous
//
#include <hip/hip_runtime.h>

typedef __fp16 f16x4 __attribute__((ext_vector_type(4)));
typedef __fp16 f16x2 __attribute__((ext_vector_type(2)));
typedef float f32x4 __attribute__((ext_vector_type(4)));

__device__ __forceinline__ f16x4 cat(f16x2 lo, f16x2 hi) {
    return __builtin_shufflevector(lo, hi, 0, 1, 2, 3);
}
__device__ __forceinline__ f16x2 u2h(unsigned v) {
    union { unsigned u; f16x2 h; } x; x.u = v; return x.h;
}
template <int CTRL>
__device__ __forceinline__ float dpp_add(float v) {
    int s = __builtin_amdgcn_update_dpp(0, __float_as_int(v), CTRL, 0xf, 0xf, true);
    return v + __int_as_float(s);
}

// async global->LDS DMA, 16B per lane; lds dest must be wave-uniform,
// data lands at lds + lane*16 (HW-fixed layout).
__device__ __forceinline__ void stage16(const float* g, float* l) {
    __builtin_amdgcn_global_load_lds(
        (const __attribute__((address_space(1))) void*)g,
        (__attribute__((address_space(3))) void*)l, 16, 0, 0);
}

// R11 counters proved: compute never stalls internally (VALUBusy == compute/dur
// exactly), and the ~17us cold-memory term is ADDITIVE with zero overlap,
// independent of register-prefetch depth (R7/R9/R10/R11). Mechanism: waves
// block at the global_load ISSUE point (per-CU miss-queue backpressure), ahead
// of any subsequent compute. Fix: stage x via the LDS-DMA engine
// (global_load_lds width=16 -- the m97 pattern), per-wave private double
// buffer, NO barriers, fine-grained s_waitcnt vmcnt(2) so the next tile's
// stage stays in flight across the compute (AITER-style, never vmcnt(0)).
// Per-sample compute body unchanged (R7): xA float4 from LDS; xB derived via
// D = x_A * I_B (C layout == B layout for 16x16x16f16); 10-step chain with
// pkrtz repack; trace reduction via 2-MFMA passes; lane-parallel polynomial.
__global__ __launch_bounds__(256) void acoef_kernel(
    const float* __restrict__ x,
    const float* __restrict__ coef,
    float* __restrict__ out,
    int B)
{
    // 4 waves x 2 bufs x 2 samples x 256 floats = 16 KB
    __shared__ float smem[4096];

    const int lane = threadIdx.x & 63;
    const int w    = threadIdx.x >> 6;
    const int n = lane & 15;
    const int q = lane >> 4;
    const bool diagsel = ((n >> 2) == q);

    const int SPB  = B / gridDim.x;          // samples per block (64)
    const int base = blockIdx.x * SPB;
    const int NT   = SPB / 8;                // 8-sample tiles per block

    // lane-constant fragments
    unsigned ilo = 0, ihi = 0;
    if (diagsel) {
        ilo = ((n & 3) == 0 ? 0x3C00u : 0u) | ((n & 3) == 1 ? 0x3C000000u : 0u);
        ihi = ((n & 3) == 2 ? 0x3C00u : 0u) | ((n & 3) == 3 ? 0x3C000000u : 0u);
    }
    const f16x4 idB = cat(u2h(ilo), u2h(ihi));
    unsigned slo = (n == 0 ? 0x3C00u : 0u) | (n == 1 ? 0x3C000000u : 0u);
    unsigned shi = (n == 2 ? 0x3C00u : 0u) | (n == 3 ? 0x3C000000u : 0u);
    const f16x4 selB  = cat(u2h(slo), u2h(shi));
    const f16x4 onesA = cat(u2h(0x3C003C00u), u2h(0x3C003C00u));
    const f32x4 zero  = {0.f, 0.f, 0.f, 0.f};

    float4 cf[3]; float scl[3];
    #pragma unroll
    for (int p = 0; p < 3; ++p) {
        int s = 4 * p + n;
        int idx = s > 9 ? 9 : s;
        cf[p]  = *(const float4*)(coef + 4 * idx);
        scl[p] = __int_as_float((127 - 8 * s) << 23);
    }

    float* lw = smem + w * 1024;     // this wave's private 4 KB (2 bufs)

    // prologue: stage tile 0 (this wave's samples 2w, 2w+1) into buf 0
    {
        const float* g = x + (size_t)(base + 2 * w) * 256 + lane * 4;
        stage16(g,       lw);
        stage16(g + 256, lw + 256);
    }

    #pragma unroll 1
    for (int t = 0; t < NT; ++t) {
        const int tn = (t + 1 < NT) ? t + 1 : t;   // clamp: redundant restage on last
        const int bc = (t & 1) * 512;
        const int bn = (~t & 1) * 512;

        // async stage of tile t+1 into the other buffer (left in flight)
        const float* g = x + (size_t)(base + tn * 8 + 2 * w) * 256 + lane * 4;
        stage16(g,       lw + bn);
        stage16(g + 256, lw + bn + 256);

        // wait for tile t's data (oldest ops) only; keep t+1's stage in flight
        asm volatile("s_waitcnt vmcnt(2)" ::: "memory");

        #pragma unroll
        for (int c = 0; c < 2; ++c) {
            const float4 a = *(const float4*)(lw + bc + c * 256 + n * 16 + q * 4);

            f16x4 xA = cat(__builtin_amdgcn_cvt_pkrtz(a.x, a.y),
                           __builtin_amdgcn_cvt_pkrtz(a.z, a.w));
            f32x4 d = __builtin_amdgcn_mfma_f32_16x16x16f16(xA, idB, zero, 0, 0, 0);
            f16x4 xB = cat(__builtin_amdgcn_cvt_pkrtz(d[0], d[1]),
                           __builtin_amdgcn_cvt_pkrtz(d[2], d[3]));

            f32x4 acc = __builtin_amdgcn_mfma_f32_16x16x16f16(xA, xB, zero, 0, 0, 0);

            f16x2 prpk[6];
            float trf = 0.0f;
            #pragma unroll
            for (int st = 0; st < 10; ++st) {
                float sA = (n & 1) ? acc[1] : acc[0];
                float sB = (n & 1) ? acc[3] : acc[2];
                float dv = (n & 2) ? sB : sA;
                float tr = diagsel ? dv : 0.0f;
                if (st & 1) prpk[st >> 1] = __builtin_amdgcn_cvt_pkrtz(trf, tr);
                else        trf = tr;

                if (st < 9) {
                    f16x4 bf = cat(__builtin_amdgcn_cvt_pkrtz(acc[0], acc[1]),
                                   __builtin_amdgcn_cvt_pkrtz(acc[2], acc[3]));
                    acc = __builtin_amdgcn_mfma_f32_16x16x16f16(xA, bf, zero, 0, 0, 0);
                }
            }
            prpk[5] = u2h(0u);

            float result = 0.0f;
            #pragma unroll
            for (int p = 0; p < 3; ++p) {
                f16x4 Ap = cat(prpk[2 * p], prpk[2 * p + 1]);
                f32x4 c1 = __builtin_amdgcn_mfma_f32_16x16x16f16(Ap, selB, zero, 0, 0, 0);
                f16x4 Bp = cat(__builtin_amdgcn_cvt_pkrtz(c1[0], c1[1]),
                               __builtin_amdgcn_cvt_pkrtz(c1[2], c1[3]));
                f32x4 c2 = __builtin_amdgcn_mfma_f32_16x16x16f16(onesA, Bp, zero, 0, 0, 0);
                float t2 = c2[0];
                float sv = t2 * 0x1p-8f;
                float h = fmaf(sv, cf[p].w, cf[p].z);
                h = fmaf(sv, h, cf[p].y);
                h = fmaf(sv, h, cf[p].x);
                result = fmaf(sv * h, scl[p], result);
            }
            result = dpp_add<0xB1>(result);
            result = dpp_add<0x4E>(result);
            if (lane == 0) out[base + t * 8 + 2 * w + c] = result;
        }
    }
}

extern "C" void kernel_launch(void* const* d_in, const int* in_sizes, int n_in,
                              void* d_out, int out_size, void* d_ws, size_t ws_size,
                              hipStream_t stream) {
    const float* x    = (const float*)d_in[0];   // [65536, 16, 16] fp32
    const float* coef = (const float*)d_in[1];   // [10, 4] fp32
    float* out        = (float*)d_out;           // [65536] fp32
    const int B = in_sizes[0] / 256;             // 65536 samples
    // 1024 blocks = 4/CU (16 waves/CU, 16 KB LDS each); 64 samples/block
    acoef_kernel<<<dim3(1024), dim3(256), 0, stream>>>(x, coef, out, B);
}